// Round 6
// baseline (321.324 us; speedup 1.0000x reference)
//
#include <hip/hip_runtime.h>

// SSIM over 11x11 gaussian-weighted patches.
// pred: [4, 2048, 16, 121, 3] f32   gt: [2048, 16, 121, 3] f32
// out:  [4, 2048, 16] f32
//
// R6 (DIAGNOSTIC): wave-private pred staging, NO __syncthreads — each wave
// stages exactly the 363-float4 slice its own 4 outputs read, so there is
// no cross-wave LDS dependency (same-wave DS ops complete in order;
// explicit s_waitcnt lgkmcnt(0) before the reads). Gaussian weights live
// in 8 registers/lane (no LDS W table). gt loaded to registers before the
// staging loads so its L2/L3 latency overlaps.
// reps=3 inner loop (identical deterministic work) so the dispatch rises
// above the ~110us fillBuffer entries and surfaces in rocprof top-5 with
// counters. Revert to reps=1 next round.

static constexpr int N_OUT    = 4 * 2048 * 16;   // 131072
static constexpr int NP_MASK  = 2048 * 16 - 1;   // 32767 (N*n_p is pow2)
static constexpr int OPB      = 16;              // outputs per block
static constexpr int FLT_BLK  = OPB * 363;       // 5808 floats of pred
static constexpr int VEC_BLK  = FLT_BLK / 4;     // 1452 float4 of pred
static constexpr int VEC_WAVE = VEC_BLK / 4;     // 363 float4 per wave slice

__device__ __constant__ float G11[11] = {
    0.00102838f, 0.00759875f, 0.03600077f, 0.10936070f, 0.21300555f,
    0.26601173f,
    0.21300555f, 0.10936070f, 0.03600077f, 0.00759875f, 0.00102838f
};

__device__ __forceinline__ float red16(float v) {
    v += __shfl_xor(v, 1);
    v += __shfl_xor(v, 2);
    v += __shfl_xor(v, 4);
    v += __shfl_xor(v, 8);
    return v;
}

__global__ __launch_bounds__(256, 4) void ssim_kernel(
    const float* __restrict__ pred, const float* __restrict__ gt,
    float* __restrict__ out, int reps)
{
    __shared__ float4 predS4[VEC_BLK];   // 23232 B; 4 disjoint wave slices

    const int t      = threadIdx.x;
    const int wave   = t >> 6;
    const int lane64 = t & 63;
    const int lane   = t & 15;
    const int group  = t >> 4;                    // 0..15
    const int o      = blockIdx.x * OPB + group;  // output index

    // per-lane gaussian weights for the 8 rounds (registers, no LDS)
    float wv[8];
    #pragma unroll
    for (int rnd = 0; rnd < 8; ++rnd) {
        const int pix = lane + rnd * 16;
        if (pix < 121) {
            const int r = pix / 11;
            const int c = pix - r * 11;
            wv[rnd] = G11[r] * G11[c];
        } else {
            wv[rnd] = 0.f;
        }
    }

    const float*  g  = gt + (size_t)(o & NP_MASK) * 363;
    const float4* p4 = (const float4*)(pred + (size_t)blockIdx.x * FLT_BLK);
    const float*  p  = (const float*)predS4 + group * 363;

    for (int rep = 0; rep < reps; ++rep) {
        // ---- gt -> registers, issued first (latency hides behind staging)
        float gv[8][3];
        #pragma unroll
        for (int rnd = 0; rnd < 8; ++rnd) {
            const int pix = lane + rnd * 16;               // 0..127
            const int pc  = (pix < 121 ? pix : 120) * 3;   // clamp: in-bounds
            gv[rnd][0] = g[pc];
            gv[rnd][1] = g[pc + 1];
            gv[rnd][2] = g[pc + 2];
        }

        // ---- wave-private pred staging: coalesced float4, no barrier ----
        #pragma unroll
        for (int r = 0; r < 6; ++r) {
            const int idx = lane64 + r * 64;
            if (idx < VEC_WAVE)
                predS4[wave * VEC_WAVE + idx] = p4[wave * VEC_WAVE + idx];
        }
        // same-wave ds_write -> ds_read ordering; wait our LDS writes only
        asm volatile("s_waitcnt lgkmcnt(0)" ::: "memory");

        // ---- compute: 16 lanes per output, pixel-per-lane ----
        float mu1[3] = {0.f, 0.f, 0.f};
        float mu2[3] = {0.f, 0.f, 0.f};
        float s1 [3] = {0.f, 0.f, 0.f};
        float s2 [3] = {0.f, 0.f, 0.f};
        float s12[3] = {0.f, 0.f, 0.f};

        #pragma unroll
        for (int rnd = 0; rnd < 8; ++rnd) {
            const int pix = lane + rnd * 16;
            const float w = wv[rnd];                       // 0 for pix >= 121
            const int pc  = (pix < 121 ? pix : 120) * 3;   // clamp: in-bounds
            const float pv[3] = {p[pc], p[pc + 1], p[pc + 2]};
            #pragma unroll
            for (int c = 0; c < 3; ++c) {
                const float pvc = pv[c];
                const float gvc = gv[rnd][c];
                const float tp = w * pvc;
                const float tg = w * gvc;
                mu1[c] += tp;
                mu2[c] += tg;
                s1 [c] = fmaf(tp, pvc, s1 [c]);
                s2 [c] = fmaf(tg, gvc, s2 [c]);
                s12[c] = fmaf(tp, gvc, s12[c]);
            }
        }

        // reduce the 15 stats across the 16-lane group
        #pragma unroll
        for (int c = 0; c < 3; ++c) {
            mu1[c] = red16(mu1[c]);
            mu2[c] = red16(mu2[c]);
            s1 [c] = red16(s1 [c]);
            s2 [c] = red16(s2 [c]);
            s12[c] = red16(s12[c]);
        }

        if (lane == 0) {
            const float C1 = 1e-4f;   // 0.01^2
            const float C2 = 9e-4f;   // 0.03^2
            float acc = 0.f;
            #pragma unroll
            for (int c = 0; c < 3; ++c) {
                const float m1 = mu1[c], m2 = mu2[c];
                const float m1sq = m1 * m1, m2sq = m2 * m2, m12 = m1 * m2;
                const float sig1 = s1[c]  - m1sq;
                const float sig2 = s2[c]  - m2sq;
                const float sg12 = s12[c] - m12;
                const float num = (2.f * m12 + C1) * (2.f * sg12 + C2);
                const float den = (m1sq + m2sq + C1) * (sig1 + sig2 + C2);
                acc += num / den;
            }
            out[o] = acc * (1.f / 3.f);
        }
    }
}

extern "C" void kernel_launch(void* const* d_in, const int* in_sizes, int n_in,
                              void* d_out, int out_size, void* d_ws, size_t ws_size,
                              hipStream_t stream) {
    const float* pred = (const float*)d_in[0];
    const float* gt   = (const float*)d_in[1];
    float* out        = (float*)d_out;
    // reps=3: diagnostic amplification so the dispatch surfaces in rocprof
    ssim_kernel<<<N_OUT / OPB, 256, 0, stream>>>(pred, gt, out, 3);
}